// Round 21
// baseline (183.981 us; speedup 1.0000x reference)
//
#include <hip/hip_runtime.h>
#include <math.h>

#define FDIM 128
#define NEG_SLOPE 0.2f
#define BCAP 10240   // k_bucket LDS sort buffer (ints)

typedef __attribute__((ext_vector_type(8))) short bf16x8;
typedef __attribute__((ext_vector_type(4))) float f32x4;

__device__ __forceinline__ float lrelu(float x) {
    return x > 0.f ? x : NEG_SLOPE * x;
}

// bf16 helpers (RNE; inputs finite)
__device__ __forceinline__ unsigned short f2bf(float f) {
    unsigned u = __float_as_uint(f);
    return (unsigned short)((u + 0x7FFFu + ((u >> 16) & 1u)) >> 16);
}
__device__ __forceinline__ float bflo(unsigned d) {
    return __uint_as_float(d << 16);
}
__device__ __forceinline__ float bfhi(unsigned d) {
    return __uint_as_float(d & 0xffff0000u);
}

// ================= atomic-free radix CSR build (R16 proven chain) =================

__global__ __launch_bounds__(256) void k_hist(const int* __restrict__ dstp,
                                              int E, int N,
                                              int* __restrict__ hist,
                                              int nb1, int nbuck) {
    __shared__ int hl[256];
    int t = threadIdx.x, blk = blockIdx.x;
    hl[t] = 0;
    __syncthreads();
    int total = E + N;
    int e0 = blk * 1024 + t * 4;
    if (e0 < total) {
        if (e0 + 3 < E) {
            int4 d4 = *(const int4*)(dstp + e0);
            atomicAdd(&hl[d4.x >> 8], 1);
            atomicAdd(&hl[d4.y >> 8], 1);
            atomicAdd(&hl[d4.z >> 8], 1);
            atomicAdd(&hl[d4.w >> 8], 1);
        } else {
#pragma unroll
            for (int q = 0; q < 4; ++q) {
                int e = e0 + q;
                if (e < total) {
                    int d = (e < E) ? dstp[e] : (e - E);
                    atomicAdd(&hl[d >> 8], 1);
                }
            }
        }
    }
    __syncthreads();
    if (t < nbuck) hist[t * nb1 + blk] = hl[t];
}

__global__ __launch_bounds__(256) void k_scan1(const int* __restrict__ in,
                                               int* __restrict__ out,
                                               int* __restrict__ bsum, int M) {
    __shared__ int sh[256];
    int b = blockIdx.x, t = threadIdx.x;
    int base = b * 1024 + t * 4;
    int4 v = make_int4(0, 0, 0, 0);
    if (base + 3 < M) v = *(const int4*)(in + base);
    else {
        if (base < M)     v.x = in[base];
        if (base + 1 < M) v.y = in[base + 1];
        if (base + 2 < M) v.z = in[base + 2];
        if (base + 3 < M) v.w = in[base + 3];
    }
    int s = v.x + v.y + v.z + v.w;
    sh[t] = s;
    __syncthreads();
    for (int off = 1; off < 256; off <<= 1) {
        int u = (t >= off) ? sh[t - off] : 0;
        __syncthreads();
        sh[t] += u;
        __syncthreads();
    }
    int excl = t ? sh[t - 1] : 0;
    if (base < M)     out[base]     = excl;
    if (base + 1 < M) out[base + 1] = excl + v.x;
    if (base + 2 < M) out[base + 2] = excl + v.x + v.y;
    if (base + 3 < M) out[base + 3] = excl + v.x + v.y + v.z;
    if (t == 255) bsum[b] = sh[255];
}

__global__ __launch_bounds__(256) void k_scan2(int* __restrict__ bsum, int nb) {
    __shared__ int sh[256];
    int t = threadIdx.x;
    int chunk = (nb + 255) >> 8;
    int b0 = t * chunk, b1 = min(b0 + chunk, nb);
    int s = 0;
    for (int i = b0; i < b1; ++i) s += bsum[i];
    sh[t] = s;
    __syncthreads();
    for (int off = 1; off < 256; off <<= 1) {
        int u = (t >= off) ? sh[t - off] : 0;
        __syncthreads();
        sh[t] += u;
        __syncthreads();
    }
    int run = t ? sh[t - 1] : 0;
    for (int i = b0; i < b1; ++i) { int v = bsum[i]; bsum[i] = run; run += v; }
}

// histScan[i] full value = hist[i] + bsum[i>>10]

__global__ __launch_bounds__(256) void k_scatter(const int* __restrict__ srcp,
                                                 const int* __restrict__ dstp,
                                                 int E, int N,
                                                 const int* __restrict__ histScan,
                                                 const int* __restrict__ bsum,
                                                 int nb1, int nbuck,
                                                 int* __restrict__ part) {
    __shared__ int baseL[256];
    __shared__ int histL[256];
    __shared__ int exclL[256];
    __shared__ int sh[256];
    __shared__ int ssrc[1024];
    __shared__ int sdst[1024];
    int t = threadIdx.x, blk = blockIdx.x;
    if (t < nbuck) {
        int idx = t * nb1 + blk;
        baseL[t] = histScan[idx] + bsum[idx >> 10];
    }
    histL[t] = 0;
    __syncthreads();
    int total = E + N;
    int e0 = blk * 1024 + t * 4;
    int src_r[4], dst_r[4];
#pragma unroll
    for (int q = 0; q < 4; ++q) { src_r[q] = 0; dst_r[q] = -1; }
    if (e0 + 3 < E) {
        int4 s4 = *(const int4*)(srcp + e0);
        int4 d4 = *(const int4*)(dstp + e0);
        src_r[0] = s4.x; src_r[1] = s4.y; src_r[2] = s4.z; src_r[3] = s4.w;
        dst_r[0] = d4.x; dst_r[1] = d4.y; dst_r[2] = d4.z; dst_r[3] = d4.w;
    } else {
#pragma unroll
        for (int q = 0; q < 4; ++q) {
            int e = e0 + q;
            if (e < total) {
                if (e < E) { src_r[q] = srcp[e]; dst_r[q] = dstp[e]; }
                else       { src_r[q] = dst_r[q] = e - E; }
            }
        }
    }
#pragma unroll
    for (int q = 0; q < 4; ++q)
        if (dst_r[q] >= 0) atomicAdd(&histL[dst_r[q] >> 8], 1);
    __syncthreads();

    sh[t] = histL[t];
    __syncthreads();
    for (int off = 1; off < 256; off <<= 1) {
        int u = (t >= off) ? sh[t - off] : 0;
        __syncthreads();
        sh[t] += u;
        __syncthreads();
    }
    exclL[t] = t ? sh[t - 1] : 0;
    __syncthreads();
    histL[t] = 0;
    __syncthreads();

#pragma unroll
    for (int q = 0; q < 4; ++q) {
        if (dst_r[q] >= 0) {
            int bin = dst_r[q] >> 8;
            int r = atomicAdd(&histL[bin], 1);
            int pos = exclL[bin] + r;
            ssrc[pos] = src_r[q];
            sdst[pos] = dst_r[q];
        }
    }
    __syncthreads();

    int eCnt = min(1024, total - blk * 1024);
    for (int i = t; i < eCnt; i += 256) {
        int d = sdst[i];
        int bin = d >> 8;
        part[baseL[bin] + (i - exclL[bin])] = (ssrc[i] << 8) | (d & 255);
    }
}

__global__ __launch_bounds__(256) void k_bucket(const int* __restrict__ part,
                                                const int* __restrict__ histScan,
                                                const int* __restrict__ bsum,
                                                int nb1, int nbuck, int E2, int N,
                                                int* __restrict__ rowp,
                                                int* __restrict__ col) {
    __shared__ int cntL[256];
    __shared__ int exclL[256];
    __shared__ int sh[256];
    __shared__ int sortbuf[BCAP];
    int b = blockIdx.x, t = threadIdx.x;
    int i0 = b * nb1;
    int s0 = histScan[i0] + bsum[i0 >> 10];
    int s1;
    if (b == nbuck - 1) s1 = E2;
    else { int i1 = (b + 1) * nb1; s1 = histScan[i1] + bsum[i1 >> 10]; }
    int sz = s1 - s0;

    cntL[t] = 0;
    __syncthreads();
    for (int i = s0 + t; i < s1; i += 256)
        atomicAdd(&cntL[part[i] & 255], 1);
    __syncthreads();

    sh[t] = cntL[t];
    __syncthreads();
    for (int off = 1; off < 256; off <<= 1) {
        int u = (t >= off) ? sh[t - off] : 0;
        __syncthreads();
        sh[t] += u;
        __syncthreads();
    }
    exclL[t] = t ? sh[t - 1] : 0;
    __syncthreads();

    int d = b * 256 + t;
    if (d < N) rowp[d] = s0 + exclL[t];
    if (b == nbuck - 1 && t == 0) rowp[N] = E2;

    cntL[t] = 0;
    __syncthreads();

    if (sz <= BCAP) {
        for (int i = s0 + t; i < s1; i += 256) {
            int p = part[i];
            int dl = p & 255;
            int r = atomicAdd(&cntL[dl], 1);
            sortbuf[exclL[dl] + r] = (int)((unsigned)p >> 8);
        }
        __syncthreads();
        for (int i = t; i < sz; i += 256)
            col[s0 + i] = sortbuf[i];
    } else {
        for (int i = s0 + t; i < s1; i += 256) {
            int p = part[i];
            int dl = p & 255;
            int r = atomicAdd(&cntL[dl], 1);
            col[s0 + exclL[dl] + r] = (int)((unsigned)p >> 8);
        }
    }
}

// ---------------- MFMA GEMM (+ fused attention scalars): 64 rows/block ----------------
// (unchanged from R20)

__global__ __launch_bounds__(256) void k_gemm(const float* __restrict__ A,
                                              const float* __restrict__ W,
                                              unsigned short* __restrict__ out,
                                              const float* __restrict__ att_s,
                                              const float* __restrict__ att_d,
                                              float* __restrict__ asrc,
                                              float* __restrict__ adst, int nrows) {
    __shared__ unsigned short Wp[32][64][8];   // 32 KB
    __shared__ float sAs[FDIM], sAd[FDIM];
    int t = threadIdx.x;
    if (t < FDIM) { sAs[t] = att_s[t]; sAd[t] = att_d[t]; }

    for (int idx = t; idx < 2048; idx += 256) {
        int tile = idx >> 6, ln = idx & 63;
        int nt = tile >> 2, kb = tile & 3;
        int k0 = kb * 32 + (ln >> 4) * 8;
        int n  = nt * 16 + (ln & 15);
#pragma unroll
        for (int i = 0; i < 8; ++i)
            Wp[tile][ln][i] = f2bf(W[(k0 + i) * FDIM + n]);
    }
    __syncthreads();

    int w = t >> 6, lane = t & 63;
    int row0 = blockIdx.x * 64 + w * 16;
    int arow = row0 + (lane & 15);
    if (arow >= nrows) arow = nrows - 1;
    int koff = (lane >> 4) * 8;

    f32x4 acc[8];
#pragma unroll
    for (int nt = 0; nt < 8; ++nt) acc[nt] = (f32x4){0.f, 0.f, 0.f, 0.f};

#pragma unroll
    for (int kb = 0; kb < 4; ++kb) {
        const float* ap = A + (size_t)arow * FDIM + kb * 32 + koff;
        float4 a0 = *(const float4*)ap;
        float4 a1 = *(const float4*)(ap + 4);
        bf16x8 af;
        af[0] = (short)f2bf(a0.x); af[1] = (short)f2bf(a0.y);
        af[2] = (short)f2bf(a0.z); af[3] = (short)f2bf(a0.w);
        af[4] = (short)f2bf(a1.x); af[5] = (short)f2bf(a1.y);
        af[6] = (short)f2bf(a1.z); af[7] = (short)f2bf(a1.w);
#pragma unroll
        for (int nt = 0; nt < 8; ++nt) {
            bf16x8 bf = *(const bf16x8*)&Wp[nt * 4 + kb][lane][0];
            acc[nt] = __builtin_amdgcn_mfma_f32_16x16x32_bf16(af, bf, acc[nt], 0, 0, 0);
        }
    }

    int crow = row0 + (lane >> 4) * 4;
    int cix  = lane & 15;

    float ps0[4] = {0,0,0,0}, ps1[4] = {0,0,0,0};
    float pd0[4] = {0,0,0,0}, pd1[4] = {0,0,0,0};
#pragma unroll
    for (int nt = 0; nt < 8; ++nt) {
        int colbase = nt * 16 + cix;
        float as_ = sAs[colbase], ad_ = sAd[colbase];
#pragma unroll
        for (int j = 0; j < 4; ++j) {
            float v = acc[nt][j];
            if (nt < 4) { ps0[j] = fmaf(v, as_, ps0[j]); pd0[j] = fmaf(v, ad_, pd0[j]); }
            else        { ps1[j] = fmaf(v, as_, ps1[j]); pd1[j] = fmaf(v, ad_, pd1[j]); }
        }
    }

#pragma unroll
    for (int j = 0; j < 4; ++j) {
        int r = crow + j;
        if (r < nrows) {
#pragma unroll
            for (int nt = 0; nt < 8; ++nt)
                out[(size_t)r * FDIM + nt * 16 + cix] = f2bf(acc[nt][j]);
        }
    }

#pragma unroll
    for (int off = 1; off < 16; off <<= 1) {
#pragma unroll
        for (int j = 0; j < 4; ++j) {
            ps0[j] += __shfl_xor(ps0[j], off);
            ps1[j] += __shfl_xor(ps1[j], off);
            pd0[j] += __shfl_xor(pd0[j], off);
            pd1[j] += __shfl_xor(pd1[j], off);
        }
    }
    if (cix == 0) {
#pragma unroll
        for (int j = 0; j < 4; ++j) {
            int r = crow + j;
            if (r < nrows) {
                asrc[2 * r]     = ps0[j];
                asrc[2 * r + 1] = ps1[j];
                adst[2 * r]     = pd0[j];
                adst[2 * r + 1] = pd1[j];
            }
        }
    }
}

// ---------------- per-dst softmax + aggregation: ONE WAVE PER NODE ----------------
// Fast path (deg<=64, ~all nodes): ALL 16 h-row loads issued right after the col
// load, BEFORE the softmax (T14 phase-level issue-early: gather addresses depend
// only on col, not on softmax). Unconditional, zero-padded (R14 lesson: no guards).
// Slow path (deg>64): R15 chunked loop (wave-uniform branch).

__global__ __launch_bounds__(256) void k_aggregate(const unsigned short* __restrict__ h,
                                                   const float* __restrict__ asrc,
                                                   const float* __restrict__ adst,
                                                   const int* __restrict__ rowp,
                                                   const int* __restrict__ col,
                                                   const float* __restrict__ bias,
                                                   float* __restrict__ outbuf,
                                                   const float* __restrict__ fcW,
                                                   const float* __restrict__ fcb,
                                                   float* __restrict__ outfin, int n) {
    __shared__ int   scol[4][64];
    __shared__ float sal[4][128];

    int t = threadIdx.x;
    int w = t >> 6;
    int lane = t & 63;
    int node = blockIdx.x * 4 + w;
    if (node >= n) return;

    int start = rowp[node];
    int deg = rowp[node + 1] - start;
    float2 adv = *(const float2*)(adst + 2 * node);
    const uint4* __restrict__ hb16 = (const uint4*)h;
    int cg_  = lane & 15;
    int hsel = (lane >> 3) & 1;
    int esel = lane >> 4;

    float p0 = 0.f, p1 = 0.f;
    float a0 = 0.f, a1 = 0.f, a2 = 0.f, a3 = 0.f;
    float a4 = 0.f, a5 = 0.f, a6 = 0.f, a7 = 0.f;

    if (__builtin_expect(deg <= 64, 1)) {
        // ---- fast path: single chunk, loads issued before softmax ----
        int s = 0;
        if (lane < deg) s = col[start + lane];
        scol[w][lane] = s;
        float2 av = make_float2(0.f, 0.f);
        if (lane < deg) av = *(const float2*)(asrc + 2 * s);   // issue asrc gather

        // issue ALL 16 h-row loads now (depend only on scol; zero-padded -> row 0)
        int sidx[16];
#pragma unroll
        for (int g = 0; g < 16; ++g) sidx[g] = scol[w][g * 4 + esel];
        uint4 hr[16];
#pragma unroll
        for (int g = 0; g < 16; ++g) hr[g] = hb16[(unsigned)sidx[g] * 16u + cg_];

        // softmax (waits only on the asrc load)
        float v0 = -1e30f, v1 = -1e30f;
        if (lane < deg) {
            v0 = lrelu(av.x + adv.x);
            v1 = lrelu(av.y + adv.y);
        }
        float m0 = v0, m1 = v1;
#pragma unroll
        for (int off = 32; off; off >>= 1) {
            m0 = fmaxf(m0, __shfl_xor(m0, off));
            m1 = fmaxf(m1, __shfl_xor(m1, off));
        }
        float e0 = 0.f, e1 = 0.f;
        if (lane < deg) { e0 = __expf(v0 - m0); e1 = __expf(v1 - m1); }
        p0 = e0; p1 = e1;
        *(float2*)&sal[w][lane * 2] = make_float2(e0, e1);

        // consume (h loads already landed or in flight)
#pragma unroll
        for (int g = 0; g < 16; ++g) {
            float al = sal[w][(g * 4 + esel) * 2 + hsel];
            uint4 hA = hr[g];
            a0 = fmaf(bflo(hA.x), al, a0); a1 = fmaf(bfhi(hA.x), al, a1);
            a2 = fmaf(bflo(hA.y), al, a2); a3 = fmaf(bfhi(hA.y), al, a3);
            a4 = fmaf(bflo(hA.z), al, a4); a5 = fmaf(bfhi(hA.z), al, a5);
            a6 = fmaf(bflo(hA.w), al, a6); a7 = fmaf(bfhi(hA.w), al, a7);
        }
    } else {
        // ---- slow path: R15 chunked loop with online rescale ----
        float m0 = -1e30f, m1 = -1e30f;
        for (int base = 0; base < deg; base += 64) {
            int cnt = min(64, deg - base);
            int s = 0;
            float v0 = -1e30f, v1 = -1e30f, e0 = 0.f, e1 = 0.f;
            if (lane < cnt) {
                s = col[start + base + lane];
                float2 av = *(const float2*)(asrc + 2 * s);
                v0 = lrelu(av.x + adv.x);
                v1 = lrelu(av.y + adv.y);
            }
            scol[w][lane] = s;
            float c0 = v0, c1 = v1;
#pragma unroll
            for (int off = 32; off; off >>= 1) {
                c0 = fmaxf(c0, __shfl_xor(c0, off));
                c1 = fmaxf(c1, __shfl_xor(c1, off));
            }
            float nm0 = fmaxf(m0, c0), nm1 = fmaxf(m1, c1);
            float r0 = __expf(m0 - nm0), r1 = __expf(m1 - nm1);
            m0 = nm0; m1 = nm1;
            p0 *= r0; p1 *= r1;
            float rmy = hsel ? r1 : r0;
            a0 *= rmy; a1 *= rmy; a2 *= rmy; a3 *= rmy;
            a4 *= rmy; a5 *= rmy; a6 *= rmy; a7 *= rmy;
            if (lane < cnt) { e0 = __expf(v0 - m0); e1 = __expf(v1 - m1); }
            p0 += e0; p1 += e1;
            *(float2*)&sal[w][lane * 2] = make_float2(e0, e1);

            int cpad = (cnt + 15) & ~15;
            for (int i = 0; i < cpad; i += 16) {
                int sA = scol[w][i + esel];
                int sB = scol[w][i + 4 + esel];
                int sC = scol[w][i + 8 + esel];
                int sD = scol[w][i + 12 + esel];
                float alA = sal[w][(i + esel) * 2 + hsel];
                float alB = sal[w][(i + 4 + esel) * 2 + hsel];
                float alC = sal[w][(i + 8 + esel) * 2 + hsel];
                float alD = sal[w][(i + 12 + esel) * 2 + hsel];
                uint4 hA = hb16[(unsigned)sA * 16u + cg_];
                uint4 hB = hb16[(unsigned)sB * 16u + cg_];
                uint4 hC = hb16[(unsigned)sC * 16u + cg_];
                uint4 hD = hb16[(unsigned)sD * 16u + cg_];
                a0 = fmaf(bflo(hA.x), alA, a0); a1 = fmaf(bfhi(hA.x), alA, a1);
                a2 = fmaf(bflo(hA.y), alA, a2); a3 = fmaf(bfhi(hA.y), alA, a3);
                a4 = fmaf(bflo(hA.z), alA, a4); a5 = fmaf(bfhi(hA.z), alA, a5);
                a6 = fmaf(bflo(hA.w), alA, a6); a7 = fmaf(bfhi(hA.w), alA, a7);
                a0 = fmaf(bflo(hB.x), alB, a0); a1 = fmaf(bfhi(hB.x), alB, a1);
                a2 = fmaf(bflo(hB.y), alB, a2); a3 = fmaf(bfhi(hB.y), alB, a3);
                a4 = fmaf(bflo(hB.z), alB, a4); a5 = fmaf(bfhi(hB.z), alB, a5);
                a6 = fmaf(bflo(hB.w), alB, a6); a7 = fmaf(bfhi(hB.w), alB, a7);
                a0 = fmaf(bflo(hC.x), alC, a0); a1 = fmaf(bfhi(hC.x), alC, a1);
                a2 = fmaf(bflo(hC.y), alC, a2); a3 = fmaf(bfhi(hC.y), alC, a3);
                a4 = fmaf(bflo(hC.z), alC, a4); a5 = fmaf(bfhi(hC.z), alC, a5);
                a6 = fmaf(bflo(hC.w), alC, a6); a7 = fmaf(bfhi(hC.w), alC, a7);
                a0 = fmaf(bflo(hD.x), alD, a0); a1 = fmaf(bfhi(hD.x), alD, a1);
                a2 = fmaf(bflo(hD.y), alD, a2); a3 = fmaf(bfhi(hD.y), alD, a3);
                a4 = fmaf(bflo(hD.z), alD, a4); a5 = fmaf(bfhi(hD.z), alD, a5);
                a6 = fmaf(bflo(hD.w), alD, a6); a7 = fmaf(bfhi(hD.w), alD, a7);
            }
        }
    }

    // combine the 4 edge slots
#pragma unroll
    for (int off = 16; off <= 32; off <<= 1) {
        a0 += __shfl_xor(a0, off); a1 += __shfl_xor(a1, off);
        a2 += __shfl_xor(a2, off); a3 += __shfl_xor(a3, off);
        a4 += __shfl_xor(a4, off); a5 += __shfl_xor(a5, off);
        a6 += __shfl_xor(a6, off); a7 += __shfl_xor(a7, off);
    }

#pragma unroll
    for (int off = 32; off; off >>= 1) {
        p0 += __shfl_xor(p0, off);
        p1 += __shfl_xor(p1, off);
    }
    float inv = hsel ? 1.f / (p1 + 1e-16f) : 1.f / (p0 + 1e-16f);
    a0 *= inv; a1 *= inv; a2 *= inv; a3 *= inv;
    a4 *= inv; a5 *= inv; a6 *= inv; a7 *= inv;

    if (lane < 16) {
        int cbase = cg_ * 8;
        float4 bv0 = *(const float4*)(bias + cbase);
        float4 bv1 = *(const float4*)(bias + cbase + 4);
        float o0 = fmaxf(a0 + bv0.x, 0.f);
        float o1 = fmaxf(a1 + bv0.y, 0.f);
        float o2 = fmaxf(a2 + bv0.z, 0.f);
        float o3 = fmaxf(a3 + bv0.w, 0.f);
        float o4 = fmaxf(a4 + bv1.x, 0.f);
        float o5 = fmaxf(a5 + bv1.y, 0.f);
        float o6 = fmaxf(a6 + bv1.z, 0.f);
        float o7 = fmaxf(a7 + bv1.w, 0.f);
        if (outbuf) {
            *(float4*)(outbuf + (size_t)node * FDIM + cbase) = make_float4(o0, o1, o2, o3);
            *(float4*)(outbuf + (size_t)node * FDIM + cbase + 4) = make_float4(o4, o5, o6, o7);
        }
        if (outfin) {
            float4 fv0 = *(const float4*)(fcW + cbase);
            float4 fv1 = *(const float4*)(fcW + cbase + 4);
            float p = fmaf(o0, fv0.x, fmaf(o1, fv0.y, fmaf(o2, fv0.z, o3 * fv0.w)));
            p = fmaf(o4, fv1.x, fmaf(o5, fv1.y, fmaf(o6, fv1.z, fmaf(o7, fv1.w, p))));
#pragma unroll
            for (int off = 8; off; off >>= 1) p += __shfl_xor(p, off);
            if (lane == 0) outfin[node] = 1.f / (1.f + __expf(-(p + fcb[0])));
        }
    }
}

// ---------------- host ----------------

static inline size_t rnd256(size_t x) { return (x + 255) & ~(size_t)255; }

extern "C" void kernel_launch(void* const* d_in, const int* in_sizes, int n_in,
                              void* d_out, int out_size, void* d_ws, size_t ws_size,
                              hipStream_t stream) {
    const float* x    = (const float*)d_in[0];
    const int*   ei   = (const int*)d_in[1];
    const float* W1   = (const float*)d_in[3];
    const float* as1  = (const float*)d_in[4];
    const float* ad1  = (const float*)d_in[5];
    const float* b1   = (const float*)d_in[6];
    const float* W2   = (const float*)d_in[7];
    const float* as2  = (const float*)d_in[8];
    const float* ad2  = (const float*)d_in[9];
    const float* b2   = (const float*)d_in[10];
    const float* fcW  = (const float*)d_in[11];
    const float* fcb  = (const float*)d_in[12];

    int N = in_sizes[0] / FDIM;
    int E = in_sizes[2];
    int E2 = E + N;
    const int* srcp = ei;
    const int* dstp = ei + E;

    int nb1   = (E2 + 1023) / 1024;
    int nbuck = (N + 255) / 256;
    int M     = nbuck * nb1;
    int sblk  = (M + 1023) / 1024;

    char* w = (char*)d_ws;
    unsigned short* hbuf = (unsigned short*)w; w += rnd256((size_t)N * FDIM * sizeof(unsigned short));
    float* obuf = (float*)w;  w += rnd256((size_t)N * FDIM * sizeof(float));
    float* asrc = (float*)w;  w += rnd256((size_t)N * 2 * sizeof(float));
    float* adst = (float*)w;  w += rnd256((size_t)N * 2 * sizeof(float));
    int* rowp = (int*)w;      w += rnd256((size_t)(N + 1) * sizeof(int));
    int* bsum = (int*)w;      w += rnd256((size_t)((M + 1023) / 1024) * sizeof(int));
    int* hist = (int*)w;      w += rnd256((size_t)M * sizeof(int));
    int* part = (int*)w;      w += rnd256((size_t)E2 * sizeof(int));
    int* col  = (int*)w;      w += rnd256((size_t)E2 * sizeof(int));

    int ggrid = (N + 63) / 64;
    int agrid = (N + 3) / 4;

    // atomic-free CSR build (R16 proven chain)
    k_hist<<<nb1, 256, 0, stream>>>(dstp, E, N, hist, nb1, nbuck);
    k_scan1<<<sblk, 256, 0, stream>>>(hist, hist, bsum, M);
    k_scan2<<<1, 256, 0, stream>>>(bsum, sblk);
    k_scatter<<<nb1, 256, 0, stream>>>(srcp, dstp, E, N, hist, bsum, nb1, nbuck, part);
    k_bucket<<<nbuck, 256, 0, stream>>>(part, hist, bsum, nb1, nbuck, E2, N, rowp, col);

    // layer 1 (MFMA gemm + fused att scalars; bf16 h)
    k_gemm<<<ggrid, 256, 0, stream>>>(x, W1, hbuf, as1, ad1, asrc, adst, N);
    k_aggregate<<<agrid, 256, 0, stream>>>(hbuf, asrc, adst, rowp, col, b1,
                                           obuf, nullptr, nullptr, nullptr, N);

    // layer 2 (fc + sigmoid fused into epilogue)
    k_gemm<<<ggrid, 256, 0, stream>>>(obuf, W2, hbuf, as2, ad2, asrc, adst, N);
    k_aggregate<<<agrid, 256, 0, stream>>>(hbuf, asrc, adst, rowp, col, b2,
                                           nullptr, fcW, fcb, (float*)d_out, N);
}

// Round 22
// 179.699 us; speedup vs baseline: 1.0238x; 1.0238x over previous
//
#include <hip/hip_runtime.h>
#include <math.h>
#include <type_traits>

#define FDIM 128
#define NEG_SLOPE 0.2f
#define BCAP 10240   // k_bucket LDS sort buffer (ints)

typedef __attribute__((ext_vector_type(8))) short bf16x8;
typedef __attribute__((ext_vector_type(4))) float f32x4;

__device__ __forceinline__ float lrelu(float x) {
    return x > 0.f ? x : NEG_SLOPE * x;
}

// bf16 helpers (RNE; inputs finite)
__device__ __forceinline__ unsigned short f2bf(float f) {
    unsigned u = __float_as_uint(f);
    return (unsigned short)((u + 0x7FFFu + ((u >> 16) & 1u)) >> 16);
}
__device__ __forceinline__ float bflo(unsigned d) {
    return __uint_as_float(d << 16);
}
__device__ __forceinline__ float bfhi(unsigned d) {
    return __uint_as_float(d & 0xffff0000u);
}

// ================= atomic-free radix CSR build (R16 proven chain) =================

__global__ __launch_bounds__(256) void k_hist(const int* __restrict__ dstp,
                                              int E, int N,
                                              int* __restrict__ hist,
                                              int nb1, int nbuck) {
    __shared__ int hl[256];
    int t = threadIdx.x, blk = blockIdx.x;
    hl[t] = 0;
    __syncthreads();
    int total = E + N;
    int e0 = blk * 1024 + t * 4;
    if (e0 < total) {
        if (e0 + 3 < E) {
            int4 d4 = *(const int4*)(dstp + e0);
            atomicAdd(&hl[d4.x >> 8], 1);
            atomicAdd(&hl[d4.y >> 8], 1);
            atomicAdd(&hl[d4.z >> 8], 1);
            atomicAdd(&hl[d4.w >> 8], 1);
        } else {
#pragma unroll
            for (int q = 0; q < 4; ++q) {
                int e = e0 + q;
                if (e < total) {
                    int d = (e < E) ? dstp[e] : (e - E);
                    atomicAdd(&hl[d >> 8], 1);
                }
            }
        }
    }
    __syncthreads();
    if (t < nbuck) hist[t * nb1 + blk] = hl[t];
}

__global__ __launch_bounds__(256) void k_scan1(const int* __restrict__ in,
                                               int* __restrict__ out,
                                               int* __restrict__ bsum, int M) {
    __shared__ int sh[256];
    int b = blockIdx.x, t = threadIdx.x;
    int base = b * 1024 + t * 4;
    int4 v = make_int4(0, 0, 0, 0);
    if (base + 3 < M) v = *(const int4*)(in + base);
    else {
        if (base < M)     v.x = in[base];
        if (base + 1 < M) v.y = in[base + 1];
        if (base + 2 < M) v.z = in[base + 2];
        if (base + 3 < M) v.w = in[base + 3];
    }
    int s = v.x + v.y + v.z + v.w;
    sh[t] = s;
    __syncthreads();
    for (int off = 1; off < 256; off <<= 1) {
        int u = (t >= off) ? sh[t - off] : 0;
        __syncthreads();
        sh[t] += u;
        __syncthreads();
    }
    int excl = t ? sh[t - 1] : 0;
    if (base < M)     out[base]     = excl;
    if (base + 1 < M) out[base + 1] = excl + v.x;
    if (base + 2 < M) out[base + 2] = excl + v.x + v.y;
    if (base + 3 < M) out[base + 3] = excl + v.x + v.y + v.z;
    if (t == 255) bsum[b] = sh[255];
}

__global__ __launch_bounds__(256) void k_scan2(int* __restrict__ bsum, int nb) {
    __shared__ int sh[256];
    int t = threadIdx.x;
    int chunk = (nb + 255) >> 8;
    int b0 = t * chunk, b1 = min(b0 + chunk, nb);
    int s = 0;
    for (int i = b0; i < b1; ++i) s += bsum[i];
    sh[t] = s;
    __syncthreads();
    for (int off = 1; off < 256; off <<= 1) {
        int u = (t >= off) ? sh[t - off] : 0;
        __syncthreads();
        sh[t] += u;
        __syncthreads();
    }
    int run = t ? sh[t - 1] : 0;
    for (int i = b0; i < b1; ++i) { int v = bsum[i]; bsum[i] = run; run += v; }
}

// histScan[i] full value = hist[i] + bsum[i>>10]

__global__ __launch_bounds__(256) void k_scatter(const int* __restrict__ srcp,
                                                 const int* __restrict__ dstp,
                                                 int E, int N,
                                                 const int* __restrict__ histScan,
                                                 const int* __restrict__ bsum,
                                                 int nb1, int nbuck,
                                                 int* __restrict__ part) {
    __shared__ int baseL[256];
    __shared__ int histL[256];
    __shared__ int exclL[256];
    __shared__ int sh[256];
    __shared__ int ssrc[1024];
    __shared__ int sdst[1024];
    int t = threadIdx.x, blk = blockIdx.x;
    if (t < nbuck) {
        int idx = t * nb1 + blk;
        baseL[t] = histScan[idx] + bsum[idx >> 10];
    }
    histL[t] = 0;
    __syncthreads();
    int total = E + N;
    int e0 = blk * 1024 + t * 4;
    int src_r[4], dst_r[4];
#pragma unroll
    for (int q = 0; q < 4; ++q) { src_r[q] = 0; dst_r[q] = -1; }
    if (e0 + 3 < E) {
        int4 s4 = *(const int4*)(srcp + e0);
        int4 d4 = *(const int4*)(dstp + e0);
        src_r[0] = s4.x; src_r[1] = s4.y; src_r[2] = s4.z; src_r[3] = s4.w;
        dst_r[0] = d4.x; dst_r[1] = d4.y; dst_r[2] = d4.z; dst_r[3] = d4.w;
    } else {
#pragma unroll
        for (int q = 0; q < 4; ++q) {
            int e = e0 + q;
            if (e < total) {
                if (e < E) { src_r[q] = srcp[e]; dst_r[q] = dstp[e]; }
                else       { src_r[q] = dst_r[q] = e - E; }
            }
        }
    }
#pragma unroll
    for (int q = 0; q < 4; ++q)
        if (dst_r[q] >= 0) atomicAdd(&histL[dst_r[q] >> 8], 1);
    __syncthreads();

    sh[t] = histL[t];
    __syncthreads();
    for (int off = 1; off < 256; off <<= 1) {
        int u = (t >= off) ? sh[t - off] : 0;
        __syncthreads();
        sh[t] += u;
        __syncthreads();
    }
    exclL[t] = t ? sh[t - 1] : 0;
    __syncthreads();
    histL[t] = 0;
    __syncthreads();

#pragma unroll
    for (int q = 0; q < 4; ++q) {
        if (dst_r[q] >= 0) {
            int bin = dst_r[q] >> 8;
            int r = atomicAdd(&histL[bin], 1);
            int pos = exclL[bin] + r;
            ssrc[pos] = src_r[q];
            sdst[pos] = dst_r[q];
        }
    }
    __syncthreads();

    int eCnt = min(1024, total - blk * 1024);
    for (int i = t; i < eCnt; i += 256) {
        int d = sdst[i];
        int bin = d >> 8;
        part[baseL[bin] + (i - exclL[bin])] = (ssrc[i] << 8) | (d & 255);
    }
}

__global__ __launch_bounds__(256) void k_bucket(const int* __restrict__ part,
                                                const int* __restrict__ histScan,
                                                const int* __restrict__ bsum,
                                                int nb1, int nbuck, int E2, int N,
                                                int* __restrict__ rowp,
                                                int* __restrict__ col) {
    __shared__ int cntL[256];
    __shared__ int exclL[256];
    __shared__ int sh[256];
    __shared__ int sortbuf[BCAP];
    int b = blockIdx.x, t = threadIdx.x;
    int i0 = b * nb1;
    int s0 = histScan[i0] + bsum[i0 >> 10];
    int s1;
    if (b == nbuck - 1) s1 = E2;
    else { int i1 = (b + 1) * nb1; s1 = histScan[i1] + bsum[i1 >> 10]; }
    int sz = s1 - s0;

    cntL[t] = 0;
    __syncthreads();
    for (int i = s0 + t; i < s1; i += 256)
        atomicAdd(&cntL[part[i] & 255], 1);
    __syncthreads();

    sh[t] = cntL[t];
    __syncthreads();
    for (int off = 1; off < 256; off <<= 1) {
        int u = (t >= off) ? sh[t - off] : 0;
        __syncthreads();
        sh[t] += u;
        __syncthreads();
    }
    exclL[t] = t ? sh[t - 1] : 0;
    __syncthreads();

    int d = b * 256 + t;
    if (d < N) rowp[d] = s0 + exclL[t];
    if (b == nbuck - 1 && t == 0) rowp[N] = E2;

    cntL[t] = 0;
    __syncthreads();

    if (sz <= BCAP) {
        for (int i = s0 + t; i < s1; i += 256) {
            int p = part[i];
            int dl = p & 255;
            int r = atomicAdd(&cntL[dl], 1);
            sortbuf[exclL[dl] + r] = (int)((unsigned)p >> 8);
        }
        __syncthreads();
        for (int i = t; i < sz; i += 256)
            col[s0 + i] = sortbuf[i];
    } else {
        for (int i = s0 + t; i < s1; i += 256) {
            int p = part[i];
            int dl = p & 255;
            int r = atomicAdd(&cntL[dl], 1);
            col[s0 + exclL[dl] + r] = (int)((unsigned)p >> 8);
        }
    }
}

// ---------------- MFMA GEMM (+ fused attention scalars): 64 rows/block ----------------
// Templated on A dtype: float (layer 1) or bf16/ushort (layer 2, reads obuf).

template <typename AT>
__global__ __launch_bounds__(256) void k_gemm(const AT* __restrict__ A,
                                              const float* __restrict__ W,
                                              unsigned short* __restrict__ out,
                                              const float* __restrict__ att_s,
                                              const float* __restrict__ att_d,
                                              float* __restrict__ asrc,
                                              float* __restrict__ adst, int nrows) {
    __shared__ unsigned short Wp[32][64][8];   // 32 KB
    __shared__ float sAs[FDIM], sAd[FDIM];
    int t = threadIdx.x;
    if (t < FDIM) { sAs[t] = att_s[t]; sAd[t] = att_d[t]; }

    for (int idx = t; idx < 2048; idx += 256) {
        int tile = idx >> 6, ln = idx & 63;
        int nt = tile >> 2, kb = tile & 3;
        int k0 = kb * 32 + (ln >> 4) * 8;
        int n  = nt * 16 + (ln & 15);
#pragma unroll
        for (int i = 0; i < 8; ++i)
            Wp[tile][ln][i] = f2bf(W[(k0 + i) * FDIM + n]);
    }
    __syncthreads();

    int w = t >> 6, lane = t & 63;
    int row0 = blockIdx.x * 64 + w * 16;
    int arow = row0 + (lane & 15);
    if (arow >= nrows) arow = nrows - 1;
    int koff = (lane >> 4) * 8;

    f32x4 acc[8];
#pragma unroll
    for (int nt = 0; nt < 8; ++nt) acc[nt] = (f32x4){0.f, 0.f, 0.f, 0.f};

#pragma unroll
    for (int kb = 0; kb < 4; ++kb) {
        bf16x8 af;
        if constexpr (std::is_same<AT, float>::value) {
            const float* ap = A + (size_t)arow * FDIM + kb * 32 + koff;
            float4 a0 = *(const float4*)ap;
            float4 a1 = *(const float4*)(ap + 4);
            af[0] = (short)f2bf(a0.x); af[1] = (short)f2bf(a0.y);
            af[2] = (short)f2bf(a0.z); af[3] = (short)f2bf(a0.w);
            af[4] = (short)f2bf(a1.x); af[5] = (short)f2bf(a1.y);
            af[6] = (short)f2bf(a1.z); af[7] = (short)f2bf(a1.w);
        } else {
            af = *(const bf16x8*)(A + (size_t)arow * FDIM + kb * 32 + koff);
        }
#pragma unroll
        for (int nt = 0; nt < 8; ++nt) {
            bf16x8 bf = *(const bf16x8*)&Wp[nt * 4 + kb][lane][0];
            acc[nt] = __builtin_amdgcn_mfma_f32_16x16x32_bf16(af, bf, acc[nt], 0, 0, 0);
        }
    }

    int crow = row0 + (lane >> 4) * 4;
    int cix  = lane & 15;

    float ps0[4] = {0,0,0,0}, ps1[4] = {0,0,0,0};
    float pd0[4] = {0,0,0,0}, pd1[4] = {0,0,0,0};
#pragma unroll
    for (int nt = 0; nt < 8; ++nt) {
        int colbase = nt * 16 + cix;
        float as_ = sAs[colbase], ad_ = sAd[colbase];
#pragma unroll
        for (int j = 0; j < 4; ++j) {
            float v = acc[nt][j];
            if (nt < 4) { ps0[j] = fmaf(v, as_, ps0[j]); pd0[j] = fmaf(v, ad_, pd0[j]); }
            else        { ps1[j] = fmaf(v, as_, ps1[j]); pd1[j] = fmaf(v, ad_, pd1[j]); }
        }
    }

#pragma unroll
    for (int j = 0; j < 4; ++j) {
        int r = crow + j;
        if (r < nrows) {
#pragma unroll
            for (int nt = 0; nt < 8; ++nt)
                out[(size_t)r * FDIM + nt * 16 + cix] = f2bf(acc[nt][j]);
        }
    }

#pragma unroll
    for (int off = 1; off < 16; off <<= 1) {
#pragma unroll
        for (int j = 0; j < 4; ++j) {
            ps0[j] += __shfl_xor(ps0[j], off);
            ps1[j] += __shfl_xor(ps1[j], off);
            pd0[j] += __shfl_xor(pd0[j], off);
            pd1[j] += __shfl_xor(pd1[j], off);
        }
    }
    if (cix == 0) {
#pragma unroll
        for (int j = 0; j < 4; ++j) {
            int r = crow + j;
            if (r < nrows) {
                asrc[2 * r]     = ps0[j];
                asrc[2 * r + 1] = ps1[j];
                adst[2 * r]     = pd0[j];
                adst[2 * r + 1] = pd1[j];
            }
        }
    }
}

// ---------------- per-dst softmax + aggregation: ONE WAVE PER NODE ----------------
// (R20-proven structure; outbuf now bf16 to halve the layer-1 output round-trip)

__global__ __launch_bounds__(256) void k_aggregate(const unsigned short* __restrict__ h,
                                                   const float* __restrict__ asrc,
                                                   const float* __restrict__ adst,
                                                   const int* __restrict__ rowp,
                                                   const int* __restrict__ col,
                                                   const float* __restrict__ bias,
                                                   unsigned short* __restrict__ outbuf,
                                                   const float* __restrict__ fcW,
                                                   const float* __restrict__ fcb,
                                                   float* __restrict__ outfin, int n) {
    __shared__ int   scol[4][64];
    __shared__ float sal[4][128];

    int t = threadIdx.x;
    int w = t >> 6;
    int lane = t & 63;
    int node = blockIdx.x * 4 + w;
    if (node >= n) return;

    int start = rowp[node];
    int deg = rowp[node + 1] - start;
    float2 adv = *(const float2*)(adst + 2 * node);
    const uint4* __restrict__ hb16 = (const uint4*)h;
    int cg_  = lane & 15;
    int hsel = (lane >> 3) & 1;
    int esel = lane >> 4;

    float m0 = -1e30f, m1 = -1e30f;
    float p0 = 0.f, p1 = 0.f;
    float a0 = 0.f, a1 = 0.f, a2 = 0.f, a3 = 0.f;
    float a4 = 0.f, a5 = 0.f, a6 = 0.f, a7 = 0.f;

    for (int base = 0; base < deg; base += 64) {
        int cnt = min(64, deg - base);
        int s = 0;
        float v0 = -1e30f, v1 = -1e30f, e0 = 0.f, e1 = 0.f;
        if (lane < cnt) {
            s = col[start + base + lane];
            float2 av = *(const float2*)(asrc + 2 * s);
            v0 = lrelu(av.x + adv.x);
            v1 = lrelu(av.y + adv.y);
        }
        scol[w][lane] = s;
        float c0 = v0, c1 = v1;
#pragma unroll
        for (int off = 32; off; off >>= 1) {
            c0 = fmaxf(c0, __shfl_xor(c0, off));
            c1 = fmaxf(c1, __shfl_xor(c1, off));
        }
        float nm0 = fmaxf(m0, c0), nm1 = fmaxf(m1, c1);
        float r0 = __expf(m0 - nm0), r1 = __expf(m1 - nm1);
        m0 = nm0; m1 = nm1;
        p0 *= r0; p1 *= r1;
        float rmy = hsel ? r1 : r0;
        a0 *= rmy; a1 *= rmy; a2 *= rmy; a3 *= rmy;
        a4 *= rmy; a5 *= rmy; a6 *= rmy; a7 *= rmy;
        if (lane < cnt) { e0 = __expf(v0 - m0); e1 = __expf(v1 - m1); }
        p0 += e0; p1 += e1;
        *(float2*)&sal[w][lane * 2] = make_float2(e0, e1);

        int cpad = (cnt + 15) & ~15;
        for (int i = 0; i < cpad; i += 16) {
            int sA = scol[w][i + esel];
            int sB = scol[w][i + 4 + esel];
            int sC = scol[w][i + 8 + esel];
            int sD = scol[w][i + 12 + esel];
            float alA = sal[w][(i + esel) * 2 + hsel];
            float alB = sal[w][(i + 4 + esel) * 2 + hsel];
            float alC = sal[w][(i + 8 + esel) * 2 + hsel];
            float alD = sal[w][(i + 12 + esel) * 2 + hsel];
            uint4 hA = hb16[(unsigned)sA * 16u + cg_];
            uint4 hB = hb16[(unsigned)sB * 16u + cg_];
            uint4 hC = hb16[(unsigned)sC * 16u + cg_];
            uint4 hD = hb16[(unsigned)sD * 16u + cg_];
            a0 = fmaf(bflo(hA.x), alA, a0); a1 = fmaf(bfhi(hA.x), alA, a1);
            a2 = fmaf(bflo(hA.y), alA, a2); a3 = fmaf(bfhi(hA.y), alA, a3);
            a4 = fmaf(bflo(hA.z), alA, a4); a5 = fmaf(bfhi(hA.z), alA, a5);
            a6 = fmaf(bflo(hA.w), alA, a6); a7 = fmaf(bfhi(hA.w), alA, a7);
            a0 = fmaf(bflo(hB.x), alB, a0); a1 = fmaf(bfhi(hB.x), alB, a1);
            a2 = fmaf(bflo(hB.y), alB, a2); a3 = fmaf(bfhi(hB.y), alB, a3);
            a4 = fmaf(bflo(hB.z), alB, a4); a5 = fmaf(bfhi(hB.z), alB, a5);
            a6 = fmaf(bflo(hB.w), alB, a6); a7 = fmaf(bfhi(hB.w), alB, a7);
            a0 = fmaf(bflo(hC.x), alC, a0); a1 = fmaf(bfhi(hC.x), alC, a1);
            a2 = fmaf(bflo(hC.y), alC, a2); a3 = fmaf(bfhi(hC.y), alC, a3);
            a4 = fmaf(bflo(hC.z), alC, a4); a5 = fmaf(bfhi(hC.z), alC, a5);
            a6 = fmaf(bflo(hC.w), alC, a6); a7 = fmaf(bfhi(hC.w), alC, a7);
            a0 = fmaf(bflo(hD.x), alD, a0); a1 = fmaf(bfhi(hD.x), alD, a1);
            a2 = fmaf(bflo(hD.y), alD, a2); a3 = fmaf(bfhi(hD.y), alD, a3);
            a4 = fmaf(bflo(hD.z), alD, a4); a5 = fmaf(bfhi(hD.z), alD, a5);
            a6 = fmaf(bflo(hD.w), alD, a6); a7 = fmaf(bfhi(hD.w), alD, a7);
        }
    }

#pragma unroll
    for (int off = 16; off <= 32; off <<= 1) {
        a0 += __shfl_xor(a0, off); a1 += __shfl_xor(a1, off);
        a2 += __shfl_xor(a2, off); a3 += __shfl_xor(a3, off);
        a4 += __shfl_xor(a4, off); a5 += __shfl_xor(a5, off);
        a6 += __shfl_xor(a6, off); a7 += __shfl_xor(a7, off);
    }

#pragma unroll
    for (int off = 32; off; off >>= 1) {
        p0 += __shfl_xor(p0, off);
        p1 += __shfl_xor(p1, off);
    }
    float inv = hsel ? 1.f / (p1 + 1e-16f) : 1.f / (p0 + 1e-16f);
    a0 *= inv; a1 *= inv; a2 *= inv; a3 *= inv;
    a4 *= inv; a5 *= inv; a6 *= inv; a7 *= inv;

    if (lane < 16) {
        int cbase = cg_ * 8;
        float4 bv0 = *(const float4*)(bias + cbase);
        float4 bv1 = *(const float4*)(bias + cbase + 4);
        float o0 = fmaxf(a0 + bv0.x, 0.f);
        float o1 = fmaxf(a1 + bv0.y, 0.f);
        float o2 = fmaxf(a2 + bv0.z, 0.f);
        float o3 = fmaxf(a3 + bv0.w, 0.f);
        float o4 = fmaxf(a4 + bv1.x, 0.f);
        float o5 = fmaxf(a5 + bv1.y, 0.f);
        float o6 = fmaxf(a6 + bv1.z, 0.f);
        float o7 = fmaxf(a7 + bv1.w, 0.f);
        if (outbuf) {
            uint4 ov;
            ov.x = ((unsigned)f2bf(o1) << 16) | f2bf(o0);
            ov.y = ((unsigned)f2bf(o3) << 16) | f2bf(o2);
            ov.z = ((unsigned)f2bf(o5) << 16) | f2bf(o4);
            ov.w = ((unsigned)f2bf(o7) << 16) | f2bf(o6);
            *(uint4*)(outbuf + (size_t)node * FDIM + cbase) = ov;
        }
        if (outfin) {
            float4 fv0 = *(const float4*)(fcW + cbase);
            float4 fv1 = *(const float4*)(fcW + cbase + 4);
            float p = fmaf(o0, fv0.x, fmaf(o1, fv0.y, fmaf(o2, fv0.z, o3 * fv0.w)));
            p = fmaf(o4, fv1.x, fmaf(o5, fv1.y, fmaf(o6, fv1.z, fmaf(o7, fv1.w, p))));
#pragma unroll
            for (int off = 8; off; off >>= 1) p += __shfl_xor(p, off);
            if (lane == 0) outfin[node] = 1.f / (1.f + __expf(-(p + fcb[0])));
        }
    }
}

// ---------------- host ----------------

static inline size_t rnd256(size_t x) { return (x + 255) & ~(size_t)255; }

extern "C" void kernel_launch(void* const* d_in, const int* in_sizes, int n_in,
                              void* d_out, int out_size, void* d_ws, size_t ws_size,
                              hipStream_t stream) {
    const float* x    = (const float*)d_in[0];
    const int*   ei   = (const int*)d_in[1];
    const float* W1   = (const float*)d_in[3];
    const float* as1  = (const float*)d_in[4];
    const float* ad1  = (const float*)d_in[5];
    const float* b1   = (const float*)d_in[6];
    const float* W2   = (const float*)d_in[7];
    const float* as2  = (const float*)d_in[8];
    const float* ad2  = (const float*)d_in[9];
    const float* b2   = (const float*)d_in[10];
    const float* fcW  = (const float*)d_in[11];
    const float* fcb  = (const float*)d_in[12];

    int N = in_sizes[0] / FDIM;
    int E = in_sizes[2];
    int E2 = E + N;
    const int* srcp = ei;
    const int* dstp = ei + E;

    int nb1   = (E2 + 1023) / 1024;
    int nbuck = (N + 255) / 256;
    int M     = nbuck * nb1;
    int sblk  = (M + 1023) / 1024;

    char* w = (char*)d_ws;
    unsigned short* hbuf = (unsigned short*)w; w += rnd256((size_t)N * FDIM * sizeof(unsigned short));
    unsigned short* obuf = (unsigned short*)w; w += rnd256((size_t)N * FDIM * sizeof(unsigned short));
    float* asrc = (float*)w;  w += rnd256((size_t)N * 2 * sizeof(float));
    float* adst = (float*)w;  w += rnd256((size_t)N * 2 * sizeof(float));
    int* rowp = (int*)w;      w += rnd256((size_t)(N + 1) * sizeof(int));
    int* bsum = (int*)w;      w += rnd256((size_t)((M + 1023) / 1024) * sizeof(int));
    int* hist = (int*)w;      w += rnd256((size_t)M * sizeof(int));
    int* part = (int*)w;      w += rnd256((size_t)E2 * sizeof(int));
    int* col  = (int*)w;      w += rnd256((size_t)E2 * sizeof(int));

    int ggrid = (N + 63) / 64;
    int agrid = (N + 3) / 4;

    // atomic-free CSR build (R16 proven chain)
    k_hist<<<nb1, 256, 0, stream>>>(dstp, E, N, hist, nb1, nbuck);
    k_scan1<<<sblk, 256, 0, stream>>>(hist, hist, bsum, M);
    k_scan2<<<1, 256, 0, stream>>>(bsum, sblk);
    k_scatter<<<nb1, 256, 0, stream>>>(srcp, dstp, E, N, hist, bsum, nb1, nbuck, part);
    k_bucket<<<nbuck, 256, 0, stream>>>(part, hist, bsum, nb1, nbuck, E2, N, rowp, col);

    // layer 1 (MFMA gemm + fused att scalars; bf16 h); obuf now bf16
    k_gemm<float><<<ggrid, 256, 0, stream>>>(x, W1, hbuf, as1, ad1, asrc, adst, N);
    k_aggregate<<<agrid, 256, 0, stream>>>(hbuf, asrc, adst, rowp, col, b1,
                                           obuf, nullptr, nullptr, nullptr, N);

    // layer 2 (MFMA gemm reads bf16 obuf; fc + sigmoid fused into agg epilogue)
    k_gemm<unsigned short><<<ggrid, 256, 0, stream>>>(obuf, W2, hbuf, as2, ad2, asrc, adst, N);
    k_aggregate<<<agrid, 256, 0, stream>>>(hbuf, asrc, adst, rowp, col, b2,
                                           nullptr, fcW, fcb, (float*)d_out, N);
}